// Round 6
// baseline (707.851 us; speedup 1.0000x reference)
//
#include <hip/hip_runtime.h>
#include <math.h>

#define D 256
#define NCODE 1024
#define NROW 65536
#define EPSF 1e-12f
#define MARGIN_REL 4e-4f   // > 2*delta; delta <= ~5e-5*||x|| (bf16-split + fp32-acc bound)

typedef __attribute__((ext_vector_type(8))) short short8;
typedef __attribute__((ext_vector_type(4))) float f32x4;

// ---------------- ws layout (floats) ----------------
// cb_n  : 0       .. 262144    (1024x256 normalized codebook, f32 row-major)
// cbp   : 262144  .. 786432    (code frags: 64 ntiles x 16 ks x 64 lanes x 8 bf16)
// i1    : 786432  .. 851968    (per-row bf16-argmax)
// v1    : 851968  .. 917504    (per-row top1 sim, raw scale)
// v2    : 917504  .. 983040    (per-row top2 sim)
// counts: 983040  .. 984064    (u32 histogram)
// loss  : 984064              (f32 accumulator)
// ---------------- out layout (floats) ----------------
// 0: loss | 1..16777217: quantized | 16777217: perplexity
// 16777218..17039362: codebook passthrough | 17039362..17104898: indices(float)
// xp (x frags, bf16 hi/lo) parked at out+4 during pack_x/gemm; overwritten by
// resolve afterwards.

__device__ __forceinline__ unsigned short bf16rne(float v) {
    unsigned u = __float_as_uint(v);
    unsigned r = u + 0x7FFFu + ((u >> 16) & 1u);
    return (unsigned short)(r >> 16);
}

__global__ __launch_bounds__(256) void normalize_cb(const float* __restrict__ w,
                                                    float* __restrict__ cb_n) {
    const int wave = threadIdx.x >> 6;
    const int lane = threadIdx.x & 63;
    const int row  = blockIdx.x * 4 + wave;
    float4 wv = *(const float4*)(w + (size_t)row * D + lane * 4);
    float s = wv.x * wv.x + wv.y * wv.y + wv.z * wv.z + wv.w * wv.w;
    #pragma unroll
    for (int off = 32; off; off >>= 1) s += __shfl_xor(s, off);
    const float scale = 1.0f / fmaxf(sqrtf(s), EPSF);
    float4 o;
    o.x = wv.x * scale; o.y = wv.y * scale; o.z = wv.z * scale; o.w = wv.w * scale;
    *(float4*)(cb_n + (size_t)row * D + lane * 4) = o;
}

// Pack a [16 x 256] f32 tile into fragment order, split hi/lo bf16.
// Frag element j of lane l, k-step ks:  src[row=(l&15)][k=ks*32+(l>>4)*8+j]
// hi -> dst[(tile*16 + ks)*64 + l], lo -> dst[(tile*16 + 8 + ks)*64 + l]
// (any slot->k map works as long as A and B packs use the SAME map)
__device__ __forceinline__ void pack_tile(const float* __restrict__ src, short8* __restrict__ dst,
                                          int tile, int ks, int lane) {
    const float* p = src + (size_t)(tile * 16 + (lane & 15)) * D + ks * 32 + ((lane >> 4) << 3);
    float4 a = *(const float4*)p;
    float4 b = *(const float4*)(p + 4);
    float va[8] = {a.x, a.y, a.z, a.w, b.x, b.y, b.z, b.w};
    short8 h, l;
    #pragma unroll
    for (int j = 0; j < 8; ++j) {
        unsigned short hb = bf16rne(va[j]);
        float hf = __uint_as_float((unsigned)hb << 16);
        unsigned short lb = bf16rne(va[j] - hf);
        h[j] = (short)hb; l[j] = (short)lb;
    }
    dst[(tile * 16 + ks) * 64 + lane]     = h;
    dst[(tile * 16 + 8 + ks) * 64 + lane] = l;
}

__global__ __launch_bounds__(256) void pack_cb(const float* __restrict__ cb_n,
                                               short8* __restrict__ cbp) {
    const int wid = blockIdx.x * 4 + (threadIdx.x >> 6);   // 512 waves: 64 ntiles x 8 ks
    pack_tile(cb_n, cbp, wid >> 3, wid & 7, threadIdx.x & 63);
}

__global__ __launch_bounds__(256) void pack_x(const float* __restrict__ x,
                                              short8* __restrict__ xp) {
    const int wid = blockIdx.x * 4 + (threadIdx.x >> 6);   // 32768 waves: 4096 xt x 8 ks
    pack_tile(x, xp, wid >> 3, wid & 7, threadIdx.x & 63);
}

// GEMM: D[code][xrow] = cb . x^T  via bf16-split (hh, hl, lh), K_eff=768.
// Block: 128 xrows x 1024 codes (8 passes of 128 codes). 4 waves = 2(codes) x 2(xrows).
// Wave tile 64x64 = 4x4 frags of 16x16x32. Per-row top-2 in registers;
// cross-wm (code-half) merge via LDS at the end.
__global__ __launch_bounds__(256) void gemm_top2(const short8* __restrict__ xp,
                                                 const short8* __restrict__ cbp,
                                                 int* __restrict__ i1g,
                                                 float* __restrict__ v1g,
                                                 float* __restrict__ v2g) {
    __shared__ float m1[2][64], m2[2][64];
    __shared__ int   mi[2][64];
    const int lane = threadIdx.x & 63, wave = threadIdx.x >> 6;
    const int wm = wave >> 1, wn = wave & 1;
    const int xtb = blockIdx.x * 8 + wn * 4;           // base xtile (of 16 rows)
    const int g = lane >> 4;                           // lane group
    const int cgrp = g * 4;

    float rv1[4], rv2[4]; int ri1[4];
    #pragma unroll
    for (int i = 0; i < 4; ++i) { rv1[i] = -3.4e38f; rv2[i] = -3.4e38f; ri1[i] = 0; }

    #pragma unroll 1
    for (int p = 0; p < 8; ++p) {
        f32x4 acc[4][4];
        const f32x4 zero = {0.f, 0.f, 0.f, 0.f};
        #pragma unroll
        for (int i = 0; i < 4; ++i)
            #pragma unroll
            for (int j = 0; j < 4; ++j) acc[i][j] = zero;

        const int ntb = p * 8 + wm * 4;                // base code-tile

        #pragma unroll 2
        for (int t = 0; t < 24; ++t) {
            const int cks = (t < 16) ? t : t - 16;     // cb k-step (0-7 hi, 8-15 lo)
            const int xks = (t < 8) ? t : t - 8;       // x  k-step (0-7 hi, 8-15 lo)
            short8 af[4], bx[4];
            #pragma unroll
            for (int fm = 0; fm < 4; ++fm)
                af[fm] = cbp[((ntb + fm) * 16 + cks) * 64 + lane];
            #pragma unroll
            for (int fn = 0; fn < 4; ++fn)
                bx[fn] = xp[((xtb + fn) * 16 + xks) * 64 + lane];
            #pragma unroll
            for (int fm = 0; fm < 4; ++fm)
                #pragma unroll
                for (int fn = 0; fn < 4; ++fn)
                    acc[fm][fn] = __builtin_amdgcn_mfma_f32_16x16x32_bf16(
                        af[fm], bx[fn], acc[fm][fn], 0, 0, 0);
        }

        // per-pass top-2 fold.  D layout: col(xrow)=lane&15, row(code)=(lane>>4)*4+reg
        const int cbase = p * 128 + wm * 64 + cgrp;
        #pragma unroll
        for (int fn = 0; fn < 4; ++fn) {
            float lv1 = -3.4e38f, lv2 = -3.4e38f; int li1 = 0;
            #pragma unroll
            for (int fm = 0; fm < 4; ++fm)
                #pragma unroll
                for (int r = 0; r < 4; ++r) {
                    const float v = acc[fm][fn][r];
                    const int code = cbase + fm * 16 + r;
                    if (v > lv1) { lv2 = lv1; lv1 = v; li1 = code; }
                    else lv2 = fmaxf(lv2, v);
                }
            // merge across the 4 lane-groups holding this column
            #pragma unroll
            for (int off = 16; off <= 32; off <<= 1) {
                const float ov1 = __shfl_xor(lv1, off);
                const float ov2 = __shfl_xor(lv2, off);
                const int   oi1 = __shfl_xor(li1, off);
                if (ov1 > lv1 || (ov1 == lv1 && oi1 < li1)) {
                    lv2 = fmaxf(lv1, ov2); lv1 = ov1; li1 = oi1;
                } else {
                    lv2 = fmaxf(lv2, ov1);
                }
            }
            // merge into running (passes ascend codes: ties keep older/lower)
            if (lv1 > rv1[fn]) { rv2[fn] = fmaxf(rv1[fn], lv2); rv1[fn] = lv1; ri1[fn] = li1; }
            else               { rv2[fn] = fmaxf(rv2[fn], lv1); }
        }
    }

    // lane l owns state fn = l>>4 for xrow = wn*64 + (l>>4)*16 + (l&15)
    float w1 = (g == 0) ? rv1[0] : (g == 1) ? rv1[1] : (g == 2) ? rv1[2] : rv1[3];
    float w2 = (g == 0) ? rv2[0] : (g == 1) ? rv2[1] : (g == 2) ? rv2[2] : rv2[3];
    int   wi = (g == 0) ? ri1[0] : (g == 1) ? ri1[1] : (g == 2) ? ri1[2] : ri1[3];

    // ---- cross-wm merge (wm=0 covers codes base+0..63, wm=1 base+64..127) ----
    if (wm == 1) { m1[wn][lane] = w1; m2[wn][lane] = w2; mi[wn][lane] = wi; }
    __syncthreads();
    if (wm == 0) {
        const float o1 = m1[wn][lane], o2 = m2[wn][lane];
        const int   oi = mi[wn][lane];
        if (o1 > w1 || (o1 == w1 && oi < wi)) { w2 = fmaxf(w1, o2); w1 = o1; wi = oi; }
        else                                  { w2 = fmaxf(w2, o1); }
        const int row = blockIdx.x * 128 + wn * 64 + g * 16 + (lane & 15);
        i1g[row] = wi; v1g[row] = w1; v2g[row] = w2;
    }
}

// Exact fp32 finish: verify/rescore argmax, loss, histogram, quantized gather.
__global__ __launch_bounds__(256) void resolve(const float* __restrict__ x,
                                               const float* __restrict__ cb_n,
                                               const int* __restrict__ i1g,
                                               const float* __restrict__ v1g,
                                               const float* __restrict__ v2g,
                                               unsigned int* __restrict__ counts,
                                               float* __restrict__ loss_acc,
                                               float* __restrict__ out_idx_f,
                                               float* __restrict__ outq) {
    __shared__ float xs[4][256];
    const int lane = threadIdx.x & 63, wave = threadIdx.x >> 6;
    float lloc = 0.f;
    #pragma unroll 1
    for (int row = blockIdx.x * 4 + wave; row < NROW; row += gridDim.x * 4) {
        const float4 xv = *(const float4*)(x + (size_t)row * D + lane * 4);
        float ss = xv.x * xv.x + xv.y * xv.y + xv.z * xv.z + xv.w * xv.w;
        #pragma unroll
        for (int off = 32; off; off >>= 1) ss += __shfl_xor(ss, off);
        const float nrm = sqrtf(ss);

        int idx = i1g[row];
        const float gap = v1g[row] - v2g[row];
        float dotv;
        if (gap >= MARGIN_REL * nrm) {
            // provably-correct argmax: one exact fp32 dot for loss
            const float4 cv = *(const float4*)(cb_n + (size_t)idx * D + lane * 4);
            float d = xv.x * cv.x + xv.y * cv.y + xv.z * cv.z + xv.w * cv.w;
            #pragma unroll
            for (int off = 32; off; off >>= 1) d += __shfl_xor(d, off);
            dotv = d;
        } else {
            // flagged: full fp32 rescore of all 1024 codes
            *(float4*)&xs[wave][lane * 4] = xv;
            asm volatile("s_waitcnt lgkmcnt(0)" ::: "memory");
            float bv = -3.4e38f; int bi = 0;
            #pragma unroll 1
            for (int c = 0; c < 16; ++c) {
                const int code = c * 64 + lane;
                const float* cr = cb_n + (size_t)code * D;
                float d = 0.f;
                #pragma unroll 4
                for (int k4 = 0; k4 < 64; ++k4) {
                    const float4 cv = *(const float4*)(cr + k4 * 4);
                    d = fmaf(xs[wave][k4 * 4 + 0], cv.x, d);
                    d = fmaf(xs[wave][k4 * 4 + 1], cv.y, d);
                    d = fmaf(xs[wave][k4 * 4 + 2], cv.z, d);
                    d = fmaf(xs[wave][k4 * 4 + 3], cv.w, d);
                }
                if (d > bv) { bv = d; bi = code; }
            }
            #pragma unroll
            for (int off = 32; off; off >>= 1) {
                const float ov = __shfl_xor(bv, off);
                const int   oi = __shfl_xor(bi, off);
                if (ov > bv || (ov == bv && oi < bi)) { bv = ov; bi = oi; }
            }
            idx = bi; dotv = bv;
        }

        const float sim = dotv / fmaxf(nrm, EPSF);
        lloc += 2.f - 2.f * sim;
        const float4 qv = *(const float4*)(cb_n + (size_t)idx * D + lane * 4);
        *(float4*)(outq + (size_t)row * D + lane * 4) = qv;
        if (lane == 0) {
            atomicAdd(&counts[idx], 1u);
            out_idx_f[row] = (float)idx;
        }
    }
    if (lane == 0) atomicAdd(loss_acc, lloc);
}

__global__ __launch_bounds__(1024) void finalize(const unsigned int* __restrict__ counts,
                                                 const float* __restrict__ loss_acc,
                                                 float* __restrict__ out_loss,
                                                 float* __restrict__ out_perp) {
    __shared__ float red[16];
    const int t = threadIdx.x;
    const float p = (float)counts[t] / 65536.0f;
    float term = p * logf(p + 1e-10f);
    #pragma unroll
    for (int off = 32; off; off >>= 1) term += __shfl_xor(term, off);
    if ((t & 63) == 0) red[t >> 6] = term;
    __syncthreads();
    if (t < 16) {
        float s = red[t];
        #pragma unroll
        for (int off = 8; off; off >>= 1) s += __shfl_xor(s, off);
        if (t == 0) {
            *out_perp = expf(-s);
            *out_loss = 1.25f * (*loss_acc) / 16777216.0f;
        }
    }
}

extern "C" void kernel_launch(void* const* d_in, const int* in_sizes, int n_in,
                              void* d_out, int out_size, void* d_ws, size_t ws_size,
                              hipStream_t stream) {
    const float* x  = (const float*)d_in[0];
    const float* cw = (const float*)d_in[1];
    float* out = (float*)d_out;
    float* ws  = (float*)d_ws;

    float*  cb_n         = ws;
    short8* cbp          = (short8*)(ws + 262144);
    int*    i1g          = (int*)(ws + 786432);
    float*  v1g          = ws + 851968;
    float*  v2g          = ws + 917504;
    unsigned int* counts = (unsigned int*)(ws + 983040);
    float*  loss_acc     = ws + 984064;

    short8* xp = (short8*)(out + 4);   // parked in quantized region (dead until resolve)

    hipMemsetAsync(counts, 0, 1025 * sizeof(float), stream);

    normalize_cb<<<256, 256, 0, stream>>>(cw, cb_n);
    pack_cb<<<128, 256, 0, stream>>>(cb_n, cbp);
    pack_x<<<8192, 256, 0, stream>>>(x, xp);
    gemm_top2<<<512, 256, 0, stream>>>(xp, cbp, i1g, v1g, v2g);
    resolve<<<2048, 256, 0, stream>>>(x, cb_n, i1g, v1g, v2g, counts, loss_acc,
                                      out + 17039362, out + 1);
    finalize<<<1, 1024, 0, stream>>>(counts, loss_acc, out, out + 16777217);
    hipMemcpyAsync(out + 16777218, cw, (size_t)NCODE * D * sizeof(float),
                   hipMemcpyDeviceToDevice, stream);
}

// Round 8
// 613.347 us; speedup vs baseline: 1.1541x; 1.1541x over previous
//
#include <hip/hip_runtime.h>
#include <math.h>

#define D 256
#define NCODE 1024
#define NROW 65536
#define EPSF 1e-12f
#define MARGIN_REL 4e-4f   // > 2*delta; delta <= ~5e-5*||x|| (bf16-split + fp32-acc bound)

typedef __attribute__((ext_vector_type(8))) short short8;
typedef __attribute__((ext_vector_type(4))) float f32x4;

// ---------------- ws layout (floats) ----------------
// cb_n  : 0       .. 262144    (1024x256 normalized codebook, f32 row-major)
// cbp   : 262144  .. 786432    (code frags: 64 ntiles x 16 ks x 64 lanes x 8 bf16)
// i1    : 786432  .. 851968    (per-row bf16-argmax)
// v1    : 851968  .. 917504    (per-row top1 sim, raw scale)
// v2    : 917504  .. 983040    (per-row top2 sim)
// counts: 983040  .. 984064    (u32 histogram)
// lp    : 984064  .. 992256    (8192 per-wave loss partials — NO single-address atomic)
// ---------------- out layout (floats) ----------------
// 0: loss | 1..16777217: quantized | 16777217: perplexity
// 16777218..17039362: codebook passthrough | 17039362..17104898: indices(float)
// xp (x frags, bf16 hi/lo) parked at out+4 during pack_x/gemm; overwritten by
// resolve afterwards.

__device__ __forceinline__ unsigned short bf16rne(float v) {
    unsigned u = __float_as_uint(v);
    unsigned r = u + 0x7FFFu + ((u >> 16) & 1u);
    return (unsigned short)(r >> 16);
}

__global__ __launch_bounds__(256) void normalize_cb(const float* __restrict__ w,
                                                    float* __restrict__ cb_n) {
    const int wave = threadIdx.x >> 6;
    const int lane = threadIdx.x & 63;
    const int row  = blockIdx.x * 4 + wave;
    float4 wv = *(const float4*)(w + (size_t)row * D + lane * 4);
    float s = wv.x * wv.x + wv.y * wv.y + wv.z * wv.z + wv.w * wv.w;
    #pragma unroll
    for (int off = 32; off; off >>= 1) s += __shfl_xor(s, off);
    const float scale = 1.0f / fmaxf(sqrtf(s), EPSF);
    float4 o;
    o.x = wv.x * scale; o.y = wv.y * scale; o.z = wv.z * scale; o.w = wv.w * scale;
    *(float4*)(cb_n + (size_t)row * D + lane * 4) = o;
}

// Pack a [16 x 256] f32 tile into fragment order, split hi/lo bf16.
// Frag element j of lane l, k-step ks:  src[row=(l&15)][k=ks*32+(l>>4)*8+j]
// hi -> dst[(tile*16 + ks)*64 + l], lo -> dst[(tile*16 + 8 + ks)*64 + l]
// (any slot->k map works as long as A and B packs use the SAME map)
__device__ __forceinline__ void pack_tile(const float* __restrict__ src, short8* __restrict__ dst,
                                          int tile, int ks, int lane) {
    const float* p = src + (size_t)(tile * 16 + (lane & 15)) * D + ks * 32 + ((lane >> 4) << 3);
    float4 a = *(const float4*)p;
    float4 b = *(const float4*)(p + 4);
    float va[8] = {a.x, a.y, a.z, a.w, b.x, b.y, b.z, b.w};
    short8 h, l;
    #pragma unroll
    for (int j = 0; j < 8; ++j) {
        unsigned short hb = bf16rne(va[j]);
        float hf = __uint_as_float((unsigned)hb << 16);
        unsigned short lb = bf16rne(va[j] - hf);
        h[j] = (short)hb; l[j] = (short)lb;
    }
    dst[(tile * 16 + ks) * 64 + lane]     = h;
    dst[(tile * 16 + 8 + ks) * 64 + lane] = l;
}

__global__ __launch_bounds__(256) void pack_cb(const float* __restrict__ cb_n,
                                               short8* __restrict__ cbp) {
    const int wid = blockIdx.x * 4 + (threadIdx.x >> 6);   // 512 waves: 64 ntiles x 8 ks
    pack_tile(cb_n, cbp, wid >> 3, wid & 7, threadIdx.x & 63);
}

__global__ __launch_bounds__(256) void pack_x(const float* __restrict__ x,
                                              short8* __restrict__ xp) {
    const int wid = blockIdx.x * 4 + (threadIdx.x >> 6);   // 32768 waves: 4096 xt x 8 ks
    pack_tile(x, xp, wid >> 3, wid & 7, threadIdx.x & 63);
}

// GEMM: D[code][xrow] = cb . x^T  via bf16-split (hh, hl, lh), K_eff=768.
// Block: 128 xrows x 1024 codes (8 passes of 128 codes). 4 waves = 2(codes) x 2(xrows).
// Wave tile 64x64 = 4x4 frags of 16x16x32. Per-row top-2 in registers;
// cross-wm (code-half) merge via LDS at the end.
__global__ __launch_bounds__(256) void gemm_top2(const short8* __restrict__ xp,
                                                 const short8* __restrict__ cbp,
                                                 int* __restrict__ i1g,
                                                 float* __restrict__ v1g,
                                                 float* __restrict__ v2g) {
    __shared__ float m1[2][64], m2[2][64];
    __shared__ int   mi[2][64];
    const int lane = threadIdx.x & 63, wave = threadIdx.x >> 6;
    const int wm = wave >> 1, wn = wave & 1;
    const int xtb = blockIdx.x * 8 + wn * 4;           // base xtile (of 16 rows)
    const int g = lane >> 4;                           // lane group
    const int cgrp = g * 4;

    float rv1[4], rv2[4]; int ri1[4];
    #pragma unroll
    for (int i = 0; i < 4; ++i) { rv1[i] = -3.4e38f; rv2[i] = -3.4e38f; ri1[i] = 0; }

    #pragma unroll 1
    for (int p = 0; p < 8; ++p) {
        f32x4 acc[4][4];
        const f32x4 zero = {0.f, 0.f, 0.f, 0.f};
        #pragma unroll
        for (int i = 0; i < 4; ++i)
            #pragma unroll
            for (int j = 0; j < 4; ++j) acc[i][j] = zero;

        const int ntb = p * 8 + wm * 4;                // base code-tile

        #pragma unroll 2
        for (int t = 0; t < 24; ++t) {
            const int cks = (t < 16) ? t : t - 16;     // cb k-step (0-7 hi, 8-15 lo)
            const int xks = (t < 8) ? t : t - 8;       // x  k-step (0-7 hi, 8-15 lo)
            short8 af[4], bx[4];
            #pragma unroll
            for (int fm = 0; fm < 4; ++fm)
                af[fm] = cbp[((ntb + fm) * 16 + cks) * 64 + lane];
            #pragma unroll
            for (int fn = 0; fn < 4; ++fn)
                bx[fn] = xp[((xtb + fn) * 16 + xks) * 64 + lane];
            #pragma unroll
            for (int fm = 0; fm < 4; ++fm)
                #pragma unroll
                for (int fn = 0; fn < 4; ++fn)
                    acc[fm][fn] = __builtin_amdgcn_mfma_f32_16x16x32_bf16(
                        af[fm], bx[fn], acc[fm][fn], 0, 0, 0);
        }

        // per-pass top-2 fold.  D layout: col(xrow)=lane&15, row(code)=(lane>>4)*4+reg
        const int cbase = p * 128 + wm * 64 + cgrp;
        #pragma unroll
        for (int fn = 0; fn < 4; ++fn) {
            float lv1 = -3.4e38f, lv2 = -3.4e38f; int li1 = 0;
            #pragma unroll
            for (int fm = 0; fm < 4; ++fm)
                #pragma unroll
                for (int r = 0; r < 4; ++r) {
                    const float v = acc[fm][fn][r];
                    const int code = cbase + fm * 16 + r;
                    if (v > lv1) { lv2 = lv1; lv1 = v; li1 = code; }
                    else lv2 = fmaxf(lv2, v);
                }
            // merge across the 4 lane-groups holding this column
            #pragma unroll
            for (int off = 16; off <= 32; off <<= 1) {
                const float ov1 = __shfl_xor(lv1, off);
                const float ov2 = __shfl_xor(lv2, off);
                const int   oi1 = __shfl_xor(li1, off);
                if (ov1 > lv1 || (ov1 == lv1 && oi1 < li1)) {
                    lv2 = fmaxf(lv1, ov2); lv1 = ov1; li1 = oi1;
                } else {
                    lv2 = fmaxf(lv2, ov1);
                }
            }
            // merge into running (passes ascend codes: ties keep older/lower)
            if (lv1 > rv1[fn]) { rv2[fn] = fmaxf(rv1[fn], lv2); rv1[fn] = lv1; ri1[fn] = li1; }
            else               { rv2[fn] = fmaxf(rv2[fn], lv1); }
        }
    }

    // lane l owns state fn = l>>4 for xrow = wn*64 + (l>>4)*16 + (l&15)
    float w1 = (g == 0) ? rv1[0] : (g == 1) ? rv1[1] : (g == 2) ? rv1[2] : rv1[3];
    float w2 = (g == 0) ? rv2[0] : (g == 1) ? rv2[1] : (g == 2) ? rv2[2] : rv2[3];
    int   wi = (g == 0) ? ri1[0] : (g == 1) ? ri1[1] : (g == 2) ? ri1[2] : ri1[3];

    // ---- cross-wm merge (wm=0 covers codes base+0..63, wm=1 base+64..127) ----
    if (wm == 1) { m1[wn][lane] = w1; m2[wn][lane] = w2; mi[wn][lane] = wi; }
    __syncthreads();
    if (wm == 0) {
        const float o1 = m1[wn][lane], o2 = m2[wn][lane];
        const int   oi = mi[wn][lane];
        if (o1 > w1 || (o1 == w1 && oi < wi)) { w2 = fmaxf(w1, o2); w1 = o1; wi = oi; }
        else                                  { w2 = fmaxf(w2, o1); }
        const int row = blockIdx.x * 128 + wn * 64 + g * 16 + (lane & 15);
        i1g[row] = wi; v1g[row] = w1; v2g[row] = w2;
    }
}

// Exact fp32 finish: verify/rescore argmax, loss, histogram, quantized gather.
// Loss partial per wave -> lp[gwid] (plain store; single-address atomics were a
// ~440us serial convoy: 8192 waves x ~130cyc LLC RMW).
__global__ __launch_bounds__(256) void resolve(const float* __restrict__ x,
                                               const float* __restrict__ cb_n,
                                               const int* __restrict__ i1g,
                                               const float* __restrict__ v1g,
                                               const float* __restrict__ v2g,
                                               unsigned int* __restrict__ counts,
                                               float* __restrict__ lp,
                                               float* __restrict__ out_idx_f,
                                               float* __restrict__ outq) {
    __shared__ float xs[4][256];
    const int lane = threadIdx.x & 63, wave = threadIdx.x >> 6;
    const int gwid = blockIdx.x * 4 + wave;
    float lloc = 0.f;
    #pragma unroll 1
    for (int row = gwid; row < NROW; row += gridDim.x * 4) {
        const float4 xv = *(const float4*)(x + (size_t)row * D + lane * 4);
        float ss = xv.x * xv.x + xv.y * xv.y + xv.z * xv.z + xv.w * xv.w;
        #pragma unroll
        for (int off = 32; off; off >>= 1) ss += __shfl_xor(ss, off);
        const float nrm = sqrtf(ss);

        int idx = i1g[row];
        const float gap = v1g[row] - v2g[row];
        float dotv;
        if (gap >= MARGIN_REL * nrm) {
            // provably-correct argmax: one exact fp32 dot for loss
            const float4 cv = *(const float4*)(cb_n + (size_t)idx * D + lane * 4);
            float d = xv.x * cv.x + xv.y * cv.y + xv.z * cv.z + xv.w * cv.w;
            #pragma unroll
            for (int off = 32; off; off >>= 1) d += __shfl_xor(d, off);
            dotv = d;
        } else {
            // flagged: full fp32 rescore of all 1024 codes
            *(float4*)&xs[wave][lane * 4] = xv;
            asm volatile("s_waitcnt lgkmcnt(0)" ::: "memory");
            float bv = -3.4e38f; int bi = 0;
            #pragma unroll 1
            for (int c = 0; c < 16; ++c) {
                const int code = c * 64 + lane;
                const float* cr = cb_n + (size_t)code * D;
                float d = 0.f;
                #pragma unroll 4
                for (int k4 = 0; k4 < 64; ++k4) {
                    const float4 cv = *(const float4*)(cr + k4 * 4);
                    d = fmaf(xs[wave][k4 * 4 + 0], cv.x, d);
                    d = fmaf(xs[wave][k4 * 4 + 1], cv.y, d);
                    d = fmaf(xs[wave][k4 * 4 + 2], cv.z, d);
                    d = fmaf(xs[wave][k4 * 4 + 3], cv.w, d);
                }
                if (d > bv) { bv = d; bi = code; }
            }
            #pragma unroll
            for (int off = 32; off; off >>= 1) {
                const float ov = __shfl_xor(bv, off);
                const int   oi = __shfl_xor(bi, off);
                if (ov > bv || (ov == bv && oi < bi)) { bv = ov; bi = oi; }
            }
            idx = bi; dotv = bv;
        }

        const float sim = dotv / fmaxf(nrm, EPSF);
        lloc += 2.f - 2.f * sim;
        const float4 qv = *(const float4*)(cb_n + (size_t)idx * D + lane * 4);
        *(float4*)(outq + (size_t)row * D + lane * 4) = qv;
        if (lane == 0) {
            atomicAdd(&counts[idx], 1u);
            out_idx_f[row] = (float)idx;
        }
    }
    if (lane == 0) lp[gwid] = lloc;
}

__global__ __launch_bounds__(1024) void finalize(const unsigned int* __restrict__ counts,
                                                 const float* __restrict__ lp,
                                                 float* __restrict__ out_loss,
                                                 float* __restrict__ out_perp) {
    __shared__ float red[16], red2[16];
    const int t = threadIdx.x;
    const float p = (float)counts[t] / 65536.0f;
    float term = p * logf(p + 1e-10f);
    float ls = 0.f;
    #pragma unroll
    for (int i = 0; i < 8; ++i) ls += lp[t + i * 1024];
    #pragma unroll
    for (int off = 32; off; off >>= 1) {
        term += __shfl_xor(term, off);
        ls   += __shfl_xor(ls, off);
    }
    if ((t & 63) == 0) { red[t >> 6] = term; red2[t >> 6] = ls; }
    __syncthreads();
    if (t < 16) {
        float s = red[t], l = red2[t];
        #pragma unroll
        for (int off = 8; off; off >>= 1) { s += __shfl_xor(s, off); l += __shfl_xor(l, off); }
        if (t == 0) {
            *out_perp = expf(-s);
            *out_loss = 1.25f * l / 16777216.0f;
        }
    }
}

extern "C" void kernel_launch(void* const* d_in, const int* in_sizes, int n_in,
                              void* d_out, int out_size, void* d_ws, size_t ws_size,
                              hipStream_t stream) {
    const float* x  = (const float*)d_in[0];
    const float* cw = (const float*)d_in[1];
    float* out = (float*)d_out;
    float* ws  = (float*)d_ws;

    float*  cb_n         = ws;
    short8* cbp          = (short8*)(ws + 262144);
    int*    i1g          = (int*)(ws + 786432);
    float*  v1g          = ws + 851968;
    float*  v2g          = ws + 917504;
    unsigned int* counts = (unsigned int*)(ws + 983040);
    float*  lp           = ws + 984064;

    short8* xp = (short8*)(out + 4);   // parked in quantized region (dead until resolve)

    hipMemsetAsync(counts, 0, 1024 * sizeof(unsigned int), stream);

    normalize_cb<<<256, 256, 0, stream>>>(cw, cb_n);
    pack_cb<<<128, 256, 0, stream>>>(cb_n, cbp);
    pack_x<<<8192, 256, 0, stream>>>(x, xp);
    gemm_top2<<<512, 256, 0, stream>>>(xp, cbp, i1g, v1g, v2g);
    resolve<<<2048, 256, 0, stream>>>(x, cb_n, i1g, v1g, v2g, counts, lp,
                                      out + 17039362, out + 1);
    finalize<<<1, 1024, 0, stream>>>(counts, lp, out, out + 16777217);
    hipMemcpyAsync(out + 16777218, cw, (size_t)NCODE * D * sizeof(float),
                   hipMemcpyDeviceToDevice, stream);
}